// Round 2
// baseline (2455.598 us; speedup 1.0000x reference)
//
#include <hip/hip_runtime.h>
#include <hip/hip_bf16.h>
#include <stdint.h>

#define DEPTH 6
#define DM 1024
#define DFF 4096
#define NH 16
#define DH 64
#define BATCH 4
#define SEQ 1024
#define NTOK (BATCH*SEQ)

using bf16x8 = __attribute__((ext_vector_type(8))) short;
using f32x4  = __attribute__((ext_vector_type(4))) float;
typedef unsigned short u16;

__device__ __forceinline__ u16 f2bf(float f) {
  union { float f; uint32_t u; } v; v.f = f;
  return (u16)((v.u + 0x7FFFu + ((v.u >> 16) & 1u)) >> 16);
}

// async global->LDS, 16B per lane. LDS dest must be wave-uniform base + lane*16,
// which holds for ptr = base + tid*16.
__device__ __forceinline__ void async16(void* lds, const void* g) {
  __builtin_amdgcn_global_load_lds(
      (__attribute__((address_space(1))) void*)(unsigned long long)g,
      (__attribute__((address_space(3))) void*)(unsigned int)(unsigned long long)lds,
      16, 0, 0);
}

// ---------------------------------------------------------------------------
// Weight convert + transpose: w f32 [K][N] -> wt bf16 [N][K]
// ---------------------------------------------------------------------------
__global__ __launch_bounds__(256)
void convT(const float* __restrict__ w, u16* __restrict__ wt, int K, int N) {
  __shared__ u16 t[32][33];
  const int n0 = blockIdx.x * 32, k0 = blockIdx.y * 32;
  const int tx = threadIdx.x & 31, ty = threadIdx.x >> 5;  // ty 0..7
  #pragma unroll
  for (int r = ty; r < 32; r += 8)
    t[r][tx] = f2bf(w[(size_t)(k0 + r) * N + n0 + tx]);
  __syncthreads();
  #pragma unroll
  for (int r = ty; r < 32; r += 8)
    wt[(size_t)(n0 + r) * K + k0 + tx] = t[tx][r];
}

// ---------------------------------------------------------------------------
// Mask all-ones flags (per batch)
// ---------------------------------------------------------------------------
__global__ void flags_init(int* flags) {
  if (threadIdx.x < BATCH) flags[threadIdx.x] = 1;
}
__global__ void mask_flags(const int* __restrict__ mask, int* __restrict__ flags) {
  const size_t n = (size_t)BATCH * SEQ * SEQ;
  for (size_t i = (size_t)blockIdx.x * 256 + threadIdx.x; i < n; i += (size_t)gridDim.x * 256)
    if (mask[i] == 0) flags[i / ((size_t)SEQ * SEQ)] = 0;
}

// ---------------------------------------------------------------------------
// Dual LayerNorm: x f32 -> o1,o2 bf16  (one block per row of 1024)
// ---------------------------------------------------------------------------
__global__ __launch_bounds__(256)
void ln_dual(const float* __restrict__ x,
             const float* __restrict__ g1, const float* __restrict__ b1v,
             const float* __restrict__ g2, const float* __restrict__ b2v,
             u16* __restrict__ o1, u16* __restrict__ o2) {
  const int row = blockIdx.x, tid = threadIdx.x;
  const float4 v = ((const float4*)(x + (size_t)row * DM))[tid];
  float s = v.x + v.y + v.z + v.w;
  float sq = v.x*v.x + v.y*v.y + v.z*v.z + v.w*v.w;
  #pragma unroll
  for (int o = 32; o; o >>= 1) { s += __shfl_xor(s, o); sq += __shfl_xor(sq, o); }
  __shared__ float red[8];
  const int lane = tid & 63, w = tid >> 6;
  if (lane == 0) { red[w] = s; red[4 + w] = sq; }
  __syncthreads();
  s = red[0] + red[1] + red[2] + red[3];
  sq = red[4] + red[5] + red[6] + red[7];
  const float mean = s * (1.0f / DM);
  const float rinv = rsqrtf(sq * (1.0f / DM) - mean * mean + 1e-5f);
  const float4 G1 = ((const float4*)g1)[tid], B1 = ((const float4*)b1v)[tid];
  const float4 G2 = ((const float4*)g2)[tid], B2 = ((const float4*)b2v)[tid];
  const float n0 = (v.x - mean) * rinv, n1 = (v.y - mean) * rinv;
  const float n2 = (v.z - mean) * rinv, n3 = (v.w - mean) * rinv;
  ushort4 a, bb;
  a.x = f2bf(n0*G1.x + B1.x); a.y = f2bf(n1*G1.y + B1.y);
  a.z = f2bf(n2*G1.z + B1.z); a.w = f2bf(n3*G1.w + B1.w);
  bb.x = f2bf(n0*G2.x + B2.x); bb.y = f2bf(n1*G2.y + B2.y);
  bb.z = f2bf(n2*G2.z + B2.z); bb.w = f2bf(n3*G2.w + B2.w);
  ((ushort4*)(o1 + (size_t)row * DM))[tid] = a;
  ((ushort4*)(o2 + (size_t)row * DM))[tid] = bb;
}

__global__ __launch_bounds__(256)
void ln_final(const float* __restrict__ x, const float* __restrict__ g,
              const float* __restrict__ b, float* __restrict__ out) {
  const int row = blockIdx.x, tid = threadIdx.x;
  const float4 v = ((const float4*)(x + (size_t)row * DM))[tid];
  float s = v.x + v.y + v.z + v.w;
  float sq = v.x*v.x + v.y*v.y + v.z*v.z + v.w*v.w;
  #pragma unroll
  for (int o = 32; o; o >>= 1) { s += __shfl_xor(s, o); sq += __shfl_xor(sq, o); }
  __shared__ float red[8];
  const int lane = tid & 63, w = tid >> 6;
  if (lane == 0) { red[w] = s; red[4 + w] = sq; }
  __syncthreads();
  s = red[0] + red[1] + red[2] + red[3];
  sq = red[4] + red[5] + red[6] + red[7];
  const float mean = s * (1.0f / DM);
  const float rinv = rsqrtf(sq * (1.0f / DM) - mean * mean + 1e-5f);
  const float4 G = ((const float4*)g)[tid], B = ((const float4*)b)[tid];
  float4 o;
  o.x = (v.x - mean) * rinv * G.x + B.x;
  o.y = (v.y - mean) * rinv * G.y + B.y;
  o.z = (v.z - mean) * rinv * G.z + B.z;
  o.w = (v.w - mean) * rinv * G.w + B.w;
  ((float4*)(out + (size_t)row * DM))[tid] = o;
}

// ---------------------------------------------------------------------------
// GEMM: C[M,N] = A[M,K](bf16) * BT[N,K]^T(bf16) + bias; m97-style 128x128 tile.
// EPI: 0 = bias->bf16, 1 = bias+relu->bf16, 2 = bias+residual add into f32 buf
// ---------------------------------------------------------------------------
template<int EPI>
__global__ __launch_bounds__(256)
void gemm_bt(const u16* __restrict__ A, const u16* __restrict__ BT,
             const float* __restrict__ bias,
             u16* __restrict__ Cb, float* __restrict__ Cf,
             int M, int N, int K) {
  __shared__ u16 As[128 * 32];
  __shared__ u16 Bs[128 * 32];
  const int tid = threadIdx.x;
  const int lane = tid & 63, wave = tid >> 6;
  const int wr = wave >> 1, wc = wave & 1;
  const int l16 = lane & 15, lhi = lane >> 4;

  const int ntn = N >> 7;
  const int nwg = (M >> 7) * ntn;
  int wg = (int)blockIdx.x;
  if ((nwg & 7) == 0) { const int q = nwg >> 3; wg = (wg & 7) * q + (wg >> 3); }
  const int tm = wg / ntn, tn = wg % ntn;

  const int srow = tid >> 2, sc = (tid & 3) * 8;
  const u16* Ag0 = A  + (size_t)(tm * 128 + srow) * K + sc;
  const u16* Bg0 = BT + (size_t)(tn * 128 + srow) * K + sc;
  const size_t rstep = (size_t)64 * K;
  u16* As0 = As + tid * 8;  u16* As1 = As + 2048 + tid * 8;
  u16* Bs0 = Bs + tid * 8;  u16* Bs1 = Bs + 2048 + tid * 8;

  f32x4 acc[4][4];
  #pragma unroll
  for (int m = 0; m < 4; m++)
    #pragma unroll
    for (int n = 0; n < 4; n++)
      #pragma unroll
      for (int j = 0; j < 4; j++) acc[m][n][j] = 0.0f;

  for (int k0 = 0; k0 < K; k0 += 32) {
    __syncthreads();
    async16(As0, Ag0 + k0);
    async16(As1, Ag0 + rstep + k0);
    async16(Bs0, Bg0 + k0);
    async16(Bs1, Bg0 + rstep + k0);
    __syncthreads();
    bf16x8 af[4], bfv[4];
    #pragma unroll
    for (int m = 0; m < 4; m++)
      af[m] = *(const bf16x8*)&As[(wr * 64 + m * 16 + l16) * 32 + lhi * 8];
    #pragma unroll
    for (int n = 0; n < 4; n++)
      bfv[n] = *(const bf16x8*)&Bs[(wc * 64 + n * 16 + l16) * 32 + lhi * 8];
    #pragma unroll
    for (int m = 0; m < 4; m++)
      #pragma unroll
      for (int n = 0; n < 4; n++)
        acc[m][n] = __builtin_amdgcn_mfma_f32_16x16x32_bf16(af[m], bfv[n], acc[m][n], 0, 0, 0);
  }

  const int row0 = tm * 128 + wr * 64 + lhi * 4;
  const int col0 = tn * 128 + wc * 64 + l16;
  #pragma unroll
  for (int n = 0; n < 4; n++) {
    const int col = col0 + n * 16;
    const float bv = bias[col];
    #pragma unroll
    for (int m = 0; m < 4; m++) {
      #pragma unroll
      for (int j = 0; j < 4; j++) {
        const int row = row0 + m * 16 + j;
        float v = acc[m][n][j] + bv;
        if constexpr (EPI == 1) v = fmaxf(v, 0.0f);
        if constexpr (EPI <= 1) Cb[(size_t)row * N + col] = f2bf(v);
        else                    Cf[(size_t)row * N + col] += v;
      }
    }
  }
}

// ---------------------------------------------------------------------------
// Flash attention: 1 block = (b,h) x 128 q-rows; 4 waves x 32 rows; KB=64.
// ---------------------------------------------------------------------------
__global__ __launch_bounds__(256)
void attn(const u16* __restrict__ Q, const u16* __restrict__ Kb,
          const u16* __restrict__ Vb, u16* __restrict__ Octx,
          const int* __restrict__ mask, const int* __restrict__ flags) {
  __shared__ u16 Ks[64 * 64];
  __shared__ u16 VT[64 * 64];
  __shared__ u16 Ps[4 * 32 * 64];
  const int tid = threadIdx.x, lane = tid & 63, wv = tid >> 6;
  const int l16 = lane & 15, lhi = lane >> 4;
  const int bid = blockIdx.x;
  const int pair = bid >> 3, qblk = bid & 7;
  const int b = pair >> 4, h = pair & 15;
  const int hoff = h * DH;
  const int q0 = qblk * 128 + wv * 32;
  const size_t tokbase = (size_t)b * SEQ;

  bf16x8 qf[2][2];
  #pragma unroll
  for (int mt = 0; mt < 2; mt++)
    #pragma unroll
    for (int ks = 0; ks < 2; ks++)
      qf[mt][ks] = *(const bf16x8*)&Q[(tokbase + q0 + mt * 16 + l16) * DM + hoff + ks * 32 + lhi * 8];

  f32x4 oacc[2][4];
  float mrun[2][4], lrun[2][4];
  #pragma unroll
  for (int mt = 0; mt < 2; mt++)
    #pragma unroll
    for (int j = 0; j < 4; j++) { mrun[mt][j] = -1e30f; lrun[mt][j] = 0.0f; }
  #pragma unroll
  for (int mt = 0; mt < 2; mt++)
    #pragma unroll
    for (int nt = 0; nt < 4; nt++)
      #pragma unroll
      for (int j = 0; j < 4; j++) oacc[mt][nt][j] = 0.0f;

  const int allone = flags[b];
  char* PwB = (char*)(Ps + wv * (32 * 64));
  char* KsB = (char*)Ks;
  char* VTB = (char*)VT;

  for (int kt = 0; kt < SEQ; kt += 64) {
    __syncthreads();
    // stage K (swizzled rows) and V^T (transpose on write, swizzled)
    #pragma unroll
    for (int p = 0; p < 2; p++) {
      const int c = tid + p * 256;
      const int rk = c >> 3, d8 = c & 7;
      const size_t goff = (tokbase + kt + rk) * DM + hoff + d8 * 8;
      bf16x8 kvv = *(const bf16x8*)&Kb[goff];
      *(bf16x8*)(KsB + ((rk * 128 + d8 * 16) ^ ((rk & 7) << 4))) = kvv;
      bf16x8 vvv = *(const bf16x8*)&Vb[goff];
      #pragma unroll
      for (int i = 0; i < 8; i++) {
        const int dr = d8 * 8 + i;
        *(u16*)(VTB + ((dr * 128 + rk * 2) ^ ((dr & 7) << 4))) = (u16)vvv[i];
      }
    }
    __syncthreads();

    // S = Q K^T  (per wave: [32 q][64 k])
    f32x4 sacc[2][4];
    #pragma unroll
    for (int mt = 0; mt < 2; mt++)
      #pragma unroll
      for (int nt = 0; nt < 4; nt++)
        #pragma unroll
        for (int j = 0; j < 4; j++) sacc[mt][nt][j] = 0.0f;
    #pragma unroll
    for (int ks = 0; ks < 2; ks++) {
      bf16x8 kf[4];
      #pragma unroll
      for (int nt = 0; nt < 4; nt++) {
        const int rk = nt * 16 + l16;
        kf[nt] = *(const bf16x8*)(KsB + ((rk * 128 + ks * 64 + lhi * 16) ^ ((rk & 7) << 4)));
      }
      #pragma unroll
      for (int mt = 0; mt < 2; mt++)
        #pragma unroll
        for (int nt = 0; nt < 4; nt++)
          sacc[mt][nt] = __builtin_amdgcn_mfma_f32_16x16x32_bf16(qf[mt][ks], kf[nt], sacc[mt][nt], 0, 0, 0);
    }

    #pragma unroll
    for (int mt = 0; mt < 2; mt++)
      #pragma unroll
      for (int nt = 0; nt < 4; nt++)
        #pragma unroll
        for (int j = 0; j < 4; j++) sacc[mt][nt][j] *= 0.125f;

    if (!allone) {  // general-mask slow path (unused when mask is all ones)
      #pragma unroll
      for (int mt = 0; mt < 2; mt++)
        #pragma unroll
        for (int j = 0; j < 4; j++) {
          const int qr = q0 + mt * 16 + lhi * 4 + j;
          #pragma unroll
          for (int nt = 0; nt < 4; nt++) {
            const int kc = kt + nt * 16 + l16;
            if (mask[(tokbase + qr) * SEQ + kc] == 0) sacc[mt][nt][j] = -1e9f;
          }
        }
    }

    // online softmax per q-row (rows live across 16-lane groups)
    #pragma unroll
    for (int mt = 0; mt < 2; mt++)
      #pragma unroll
      for (int j = 0; j < 4; j++) {
        float tmax = fmaxf(fmaxf(sacc[mt][0][j], sacc[mt][1][j]),
                           fmaxf(sacc[mt][2][j], sacc[mt][3][j]));
        #pragma unroll
        for (int m_ = 1; m_ < 16; m_ <<= 1) tmax = fmaxf(tmax, __shfl_xor(tmax, m_));
        const float mnew = fmaxf(mrun[mt][j], tmax);
        const float corr = __expf(mrun[mt][j] - mnew);
        const float p0 = __expf(sacc[mt][0][j] - mnew);
        const float p1 = __expf(sacc[mt][1][j] - mnew);
        const float p2 = __expf(sacc[mt][2][j] - mnew);
        const float p3 = __expf(sacc[mt][3][j] - mnew);
        float tsum = p0 + p1 + p2 + p3;
        #pragma unroll
        for (int m_ = 1; m_ < 16; m_ <<= 1) tsum += __shfl_xor(tsum, m_);
        lrun[mt][j] = lrun[mt][j] * corr + tsum;
        mrun[mt][j] = mnew;
        #pragma unroll
        for (int nt = 0; nt < 4; nt++) oacc[mt][nt][j] *= corr;
        const int rp = mt * 16 + lhi * 4 + j;
        const int xw = (rp & 7) << 4;
        const int base = rp * 128 + l16 * 2;
        *(u16*)(PwB + ((base +  0) ^ xw)) = f2bf(p0);
        *(u16*)(PwB + ((base + 32) ^ xw)) = f2bf(p1);
        *(u16*)(PwB + ((base + 64) ^ xw)) = f2bf(p2);
        *(u16*)(PwB + ((base + 96) ^ xw)) = f2bf(p3);
      }

    // O += P V
    #pragma unroll
    for (int ks = 0; ks < 2; ks++) {
      bf16x8 vf[4];
      #pragma unroll
      for (int nt = 0; nt < 4; nt++) {
        const int dr = nt * 16 + l16;
        vf[nt] = *(const bf16x8*)(VTB + ((dr * 128 + ks * 64 + lhi * 16) ^ ((dr & 7) << 4)));
      }
      #pragma unroll
      for (int mt = 0; mt < 2; mt++) {
        const int rp = mt * 16 + l16;
        bf16x8 pf = *(const bf16x8*)(PwB + ((rp * 128 + ks * 64 + lhi * 16) ^ ((rp & 7) << 4)));
        #pragma unroll
        for (int nt = 0; nt < 4; nt++)
          oacc[mt][nt] = __builtin_amdgcn_mfma_f32_16x16x32_bf16(pf, vf[nt], oacc[mt][nt], 0, 0, 0);
      }
    }
  }

  #pragma unroll
  for (int mt = 0; mt < 2; mt++)
    #pragma unroll
    for (int j = 0; j < 4; j++) {
      const float inv = 1.0f / lrun[mt][j];
      const size_t rowg = (tokbase + q0 + mt * 16 + lhi * 4 + j) * DM + hoff;
      #pragma unroll
      for (int nt = 0; nt < 4; nt++)
        Octx[rowg + nt * 16 + l16] = f2bf(oacc[mt][nt][j] * inv);
    }
}

// ---------------------------------------------------------------------------
// Orchestration
// ---------------------------------------------------------------------------
extern "C" void kernel_launch(void* const* d_in, const int* in_sizes, int n_in,
                              void* d_out, int out_size, void* d_ws, size_t ws_size,
                              hipStream_t stream) {
  const float* x    = (const float*)d_in[0];
  const int*   mask = (const int*)d_in[1];
  const float* wq = (const float*)d_in[2];
  const float* bq = (const float*)d_in[3];
  const float* wk = (const float*)d_in[4];
  const float* bk = (const float*)d_in[5];
  const float* wvp = (const float*)d_in[6];
  const float* bv = (const float*)d_in[7];
  const float* wo = (const float*)d_in[8];
  const float* bo = (const float*)d_in[9];
  const float* w1 = (const float*)d_in[10];
  const float* b1 = (const float*)d_in[11];
  const float* w2 = (const float*)d_in[12];
  const float* b2 = (const float*)d_in[13];
  const float* ln1g = (const float*)d_in[14];
  const float* ln1b = (const float*)d_in[15];
  const float* ln2g = (const float*)d_in[16];
  const float* ln2b = (const float*)d_in[17];
  const float* lnfg = (const float*)d_in[18];
  const float* lnfb = (const float*)d_in[19];

  char* ws = (char*)d_ws;
  float* xbuf = (float*)(ws);                       // 16 MB f32 residual stream
  u16* xn1 = (u16*)(ws + ((size_t)16 << 20));       // 8 MB
  u16* xn2 = (u16*)(ws + ((size_t)24 << 20));       // 8 MB
  u16* qb  = (u16*)(ws + ((size_t)32 << 20));       // 8 MB
  u16* kb  = (u16*)(ws + ((size_t)40 << 20));       // 8 MB
  u16* vb  = (u16*)(ws + ((size_t)48 << 20));       // 8 MB
  u16* ctx = (u16*)(ws + ((size_t)56 << 20));       // 8 MB
  u16* hb  = qb;                                    // 32 MB alias over qb..ctx
  u16* wqT = (u16*)(ws + ((size_t)64 << 20));       // 2 MB each
  u16* wkT = (u16*)(ws + ((size_t)66 << 20));
  u16* wvT = (u16*)(ws + ((size_t)68 << 20));
  u16* woT = (u16*)(ws + ((size_t)70 << 20));
  u16* w1T = (u16*)(ws + ((size_t)72 << 20));       // 8 MB
  u16* w2T = (u16*)(ws + ((size_t)80 << 20));       // 8 MB
  int* flags = (int*)(ws + ((size_t)88 << 20));

  hipMemcpyAsync(xbuf, x, (size_t)NTOK * DM * sizeof(float),
                 hipMemcpyDeviceToDevice, stream);
  flags_init<<<1, 64, 0, stream>>>(flags);
  mask_flags<<<1024, 256, 0, stream>>>(mask, flags);

  // grid for a [M,N] GEMM with 128x128 tiles — ALWAYS computed, never hardcoded
  // (round-1 bug: w2 launched with 1024 wgs for a 256-wg problem -> colliding
  //  tiles under the XCD swizzle + '+=' epilogue double-accumulated)
  auto wgs = [](int M, int N) { return dim3((unsigned)((M >> 7) * (N >> 7))); };

  for (int i = 0; i < DEPTH; i++) {
    convT<<<dim3(32, 32),  256, 0, stream>>>(wq  + (size_t)i * DM * DM,  wqT, DM,  DM);
    convT<<<dim3(32, 32),  256, 0, stream>>>(wk  + (size_t)i * DM * DM,  wkT, DM,  DM);
    convT<<<dim3(32, 32),  256, 0, stream>>>(wvp + (size_t)i * DM * DM,  wvT, DM,  DM);
    convT<<<dim3(32, 32),  256, 0, stream>>>(wo  + (size_t)i * DM * DM,  woT, DM,  DM);
    convT<<<dim3(128, 32), 256, 0, stream>>>(w1  + (size_t)i * DM * DFF, w1T, DM,  DFF);
    convT<<<dim3(32, 128), 256, 0, stream>>>(w2  + (size_t)i * DFF * DM, w2T, DFF, DM);

    ln_dual<<<NTOK, 256, 0, stream>>>(xbuf, ln1g + i * DM, ln1b + i * DM,
                                      ln2g + i * DM, ln2b + i * DM, xn1, xn2);

    gemm_bt<0><<<wgs(NTOK, DM), 256, 0, stream>>>(xn1, wqT, bq + i * DM, qb, nullptr, NTOK, DM, DM);
    gemm_bt<0><<<wgs(NTOK, DM), 256, 0, stream>>>(xn1, wkT, bk + i * DM, kb, nullptr, NTOK, DM, DM);
    gemm_bt<0><<<wgs(NTOK, DM), 256, 0, stream>>>(xn1, wvT, bv + i * DM, vb, nullptr, NTOK, DM, DM);

    attn<<<512, 256, 0, stream>>>(qb, kb, vb, ctx, mask, flags);

    gemm_bt<2><<<wgs(NTOK, DM), 256, 0, stream>>>(ctx, woT, bo + i * DM, nullptr, xbuf, NTOK, DM, DM);
    gemm_bt<1><<<wgs(NTOK, DFF), 256, 0, stream>>>(xn2, w1T, b1 + i * DFF, hb, nullptr, NTOK, DFF, DM);
    gemm_bt<2><<<wgs(NTOK, DM), 256, 0, stream>>>(hb, w2T, b2 + i * DM, nullptr, xbuf, NTOK, DM, DFF);
  }

  ln_final<<<NTOK, 256, 0, stream>>>(xbuf, lnfg, lnfb, (float*)d_out);
}

// Round 3
// 1921.124 us; speedup vs baseline: 1.2782x; 1.2782x over previous
//
#include <hip/hip_runtime.h>
#include <hip/hip_bf16.h>
#include <stdint.h>

#define DEPTH 6
#define DM 1024
#define DFF 4096
#define NH 16
#define DH 64
#define BATCH 4
#define SEQ 1024
#define NTOK (BATCH*SEQ)
#define QKVLD 3072

using bf16x8 = __attribute__((ext_vector_type(8))) short;
using f32x4  = __attribute__((ext_vector_type(4))) float;
typedef unsigned short u16;

__device__ __forceinline__ u16 f2bf(float f) {
  union { float f; uint32_t u; } v; v.f = f;
  return (u16)((v.u + 0x7FFFu + ((v.u >> 16) & 1u)) >> 16);
}

// async global->LDS, 16B per lane. LDS dest must be wave-uniform base + lane*16.
__device__ __forceinline__ void async16(void* lds, const void* g) {
  __builtin_amdgcn_global_load_lds(
      (__attribute__((address_space(1))) void*)(unsigned long long)g,
      (__attribute__((address_space(3))) void*)(unsigned int)(unsigned long long)lds,
      16, 0, 0);
}

// ---------------------------------------------------------------------------
// Weight convert + transpose: w f32 [K][N] -> wt bf16 [N][K]
// ---------------------------------------------------------------------------
__global__ __launch_bounds__(256)
void convT(const float* __restrict__ w, u16* __restrict__ wt, int K, int N) {
  __shared__ u16 t[32][33];
  const int n0 = blockIdx.x * 32, k0 = blockIdx.y * 32;
  const int tx = threadIdx.x & 31, ty = threadIdx.x >> 5;
  #pragma unroll
  for (int r = ty; r < 32; r += 8)
    t[r][tx] = f2bf(w[(size_t)(k0 + r) * N + n0 + tx]);
  __syncthreads();
  #pragma unroll
  for (int r = ty; r < 32; r += 8)
    wt[(size_t)(n0 + r) * K + k0 + tx] = t[tx][r];
}

// ---------------------------------------------------------------------------
// bias concat bq|bk|bv -> bqkv[3072]
// ---------------------------------------------------------------------------
__global__ void bcat(const float* __restrict__ bq, const float* __restrict__ bk,
                     const float* __restrict__ bv, float* __restrict__ out) {
  const int t = blockIdx.x * 256 + threadIdx.x;
  if (t < 1024) out[t] = bq[t];
  else if (t < 2048) out[t] = bk[t - 1024];
  else if (t < 3072) out[t] = bv[t - 2048];
}

// ---------------------------------------------------------------------------
// V-transpose: qkv[tok][3072] section 2048.. -> vt[(b*1024+hd)][s]  (bf16)
// ---------------------------------------------------------------------------
__global__ __launch_bounds__(256)
void vtrans(const u16* __restrict__ qkv, u16* __restrict__ vt) {
  __shared__ u16 t[64][72];
  const int s0 = blockIdx.x * 64, c0 = blockIdx.y * 64, b = blockIdx.z;
  const int r = threadIdx.x >> 2, cq = threadIdx.x & 3;
  const u16* src = qkv + ((size_t)(b * SEQ + s0 + r)) * QKVLD + 2048 + c0 + cq * 16;
  *(bf16x8*)&t[r][cq * 16]     = *(const bf16x8*)(src);
  *(bf16x8*)&t[r][cq * 16 + 8] = *(const bf16x8*)(src + 8);
  __syncthreads();
  bf16x8 a, bvec;
  #pragma unroll
  for (int i = 0; i < 8; i++) a[i] = (short)t[cq * 16 + i][r];
  #pragma unroll
  for (int i = 0; i < 8; i++) bvec[i] = (short)t[cq * 16 + 8 + i][r];
  u16* dst = vt + ((size_t)(b * 1024 + c0 + r)) * SEQ + s0 + cq * 16;
  *(bf16x8*)dst = a;
  *(bf16x8*)(dst + 8) = bvec;
}

// ---------------------------------------------------------------------------
// Mask all-ones flags (per batch)
// ---------------------------------------------------------------------------
__global__ void flags_init(int* flags) {
  if (threadIdx.x < BATCH) flags[threadIdx.x] = 1;
}
__global__ void mask_flags(const int* __restrict__ mask, int* __restrict__ flags) {
  const size_t n = (size_t)BATCH * SEQ * SEQ;
  for (size_t i = (size_t)blockIdx.x * 256 + threadIdx.x; i < n; i += (size_t)gridDim.x * 256)
    if (mask[i] == 0) flags[i / ((size_t)SEQ * SEQ)] = 0;
}

// ---------------------------------------------------------------------------
// Dual LayerNorm: x f32 -> o1,o2 bf16
// ---------------------------------------------------------------------------
__global__ __launch_bounds__(256)
void ln_dual(const float* __restrict__ x,
             const float* __restrict__ g1, const float* __restrict__ b1v,
             const float* __restrict__ g2, const float* __restrict__ b2v,
             u16* __restrict__ o1, u16* __restrict__ o2) {
  const int row = blockIdx.x, tid = threadIdx.x;
  const float4 v = ((const float4*)(x + (size_t)row * DM))[tid];
  float s = v.x + v.y + v.z + v.w;
  float sq = v.x*v.x + v.y*v.y + v.z*v.z + v.w*v.w;
  #pragma unroll
  for (int o = 32; o; o >>= 1) { s += __shfl_xor(s, o); sq += __shfl_xor(sq, o); }
  __shared__ float red[8];
  const int lane = tid & 63, w = tid >> 6;
  if (lane == 0) { red[w] = s; red[4 + w] = sq; }
  __syncthreads();
  s = red[0] + red[1] + red[2] + red[3];
  sq = red[4] + red[5] + red[6] + red[7];
  const float mean = s * (1.0f / DM);
  const float rinv = rsqrtf(sq * (1.0f / DM) - mean * mean + 1e-5f);
  const float4 G1 = ((const float4*)g1)[tid], B1 = ((const float4*)b1v)[tid];
  const float4 G2 = ((const float4*)g2)[tid], B2 = ((const float4*)b2v)[tid];
  const float n0 = (v.x - mean) * rinv, n1 = (v.y - mean) * rinv;
  const float n2 = (v.z - mean) * rinv, n3 = (v.w - mean) * rinv;
  ushort4 a, bb;
  a.x = f2bf(n0*G1.x + B1.x); a.y = f2bf(n1*G1.y + B1.y);
  a.z = f2bf(n2*G1.z + B1.z); a.w = f2bf(n3*G1.w + B1.w);
  bb.x = f2bf(n0*G2.x + B2.x); bb.y = f2bf(n1*G2.y + B2.y);
  bb.z = f2bf(n2*G2.z + B2.z); bb.w = f2bf(n3*G2.w + B2.w);
  ((ushort4*)(o1 + (size_t)row * DM))[tid] = a;
  ((ushort4*)(o2 + (size_t)row * DM))[tid] = bb;
}

__global__ __launch_bounds__(256)
void ln_final(const float* __restrict__ x, const float* __restrict__ g,
              const float* __restrict__ b, float* __restrict__ out) {
  const int row = blockIdx.x, tid = threadIdx.x;
  const float4 v = ((const float4*)(x + (size_t)row * DM))[tid];
  float s = v.x + v.y + v.z + v.w;
  float sq = v.x*v.x + v.y*v.y + v.z*v.z + v.w*v.w;
  #pragma unroll
  for (int o = 32; o; o >>= 1) { s += __shfl_xor(s, o); sq += __shfl_xor(sq, o); }
  __shared__ float red[8];
  const int lane = tid & 63, w = tid >> 6;
  if (lane == 0) { red[w] = s; red[4 + w] = sq; }
  __syncthreads();
  s = red[0] + red[1] + red[2] + red[3];
  sq = red[4] + red[5] + red[6] + red[7];
  const float mean = s * (1.0f / DM);
  const float rinv = rsqrtf(sq * (1.0f / DM) - mean * mean + 1e-5f);
  const float4 G = ((const float4*)g)[tid], B = ((const float4*)b)[tid];
  float4 o;
  o.x = (v.x - mean) * rinv * G.x + B.x;
  o.y = (v.y - mean) * rinv * G.y + B.y;
  o.z = (v.z - mean) * rinv * G.z + B.z;
  o.w = (v.w - mean) * rinv * G.w + B.w;
  ((float4*)(out + (size_t)row * DM))[tid] = o;
}

// ---------------------------------------------------------------------------
// GEMM: C[M,N] = A[M,K](bf16) * BT[N,K]^T(bf16) + bias; m97-style 128x128 tile.
// EPI: 0 = bias->bf16, 1 = bias+relu->bf16, 2 = bias+residual add into f32 buf
// ---------------------------------------------------------------------------
template<int EPI>
__global__ __launch_bounds__(256)
void gemm_bt(const u16* __restrict__ A, const u16* __restrict__ BT,
             const float* __restrict__ bias,
             u16* __restrict__ Cb, float* __restrict__ Cf,
             int M, int N, int K) {
  __shared__ u16 As[128 * 32];
  __shared__ u16 Bs[128 * 32];
  const int tid = threadIdx.x;
  const int lane = tid & 63, wave = tid >> 6;
  const int wr = wave >> 1, wc = wave & 1;
  const int l16 = lane & 15, lhi = lane >> 4;

  const int ntn = N >> 7;
  const int nwg = (M >> 7) * ntn;
  int wg = (int)blockIdx.x;
  if ((nwg & 7) == 0) { const int q = nwg >> 3; wg = (wg & 7) * q + (wg >> 3); }
  const int tm = wg / ntn, tn = wg % ntn;

  const int srow = tid >> 2, sc = (tid & 3) * 8;
  const u16* Ag0 = A  + (size_t)(tm * 128 + srow) * K + sc;
  const u16* Bg0 = BT + (size_t)(tn * 128 + srow) * K + sc;
  const size_t rstep = (size_t)64 * K;
  u16* As0 = As + tid * 8;  u16* As1 = As + 2048 + tid * 8;
  u16* Bs0 = Bs + tid * 8;  u16* Bs1 = Bs + 2048 + tid * 8;

  f32x4 acc[4][4];
  #pragma unroll
  for (int m = 0; m < 4; m++)
    #pragma unroll
    for (int n = 0; n < 4; n++)
      #pragma unroll
      for (int j = 0; j < 4; j++) acc[m][n][j] = 0.0f;

  for (int k0 = 0; k0 < K; k0 += 32) {
    __syncthreads();
    async16(As0, Ag0 + k0);
    async16(As1, Ag0 + rstep + k0);
    async16(Bs0, Bg0 + k0);
    async16(Bs1, Bg0 + rstep + k0);
    __syncthreads();
    bf16x8 af[4], bfv[4];
    #pragma unroll
    for (int m = 0; m < 4; m++)
      af[m] = *(const bf16x8*)&As[(wr * 64 + m * 16 + l16) * 32 + lhi * 8];
    #pragma unroll
    for (int n = 0; n < 4; n++)
      bfv[n] = *(const bf16x8*)&Bs[(wc * 64 + n * 16 + l16) * 32 + lhi * 8];
    #pragma unroll
    for (int m = 0; m < 4; m++)
      #pragma unroll
      for (int n = 0; n < 4; n++)
        acc[m][n] = __builtin_amdgcn_mfma_f32_16x16x32_bf16(af[m], bfv[n], acc[m][n], 0, 0, 0);
  }

  const int row0 = tm * 128 + wr * 64 + lhi * 4;
  const int col0 = tn * 128 + wc * 64 + l16;
  #pragma unroll
  for (int n = 0; n < 4; n++) {
    const int col = col0 + n * 16;
    const float bv = bias[col];
    #pragma unroll
    for (int m = 0; m < 4; m++) {
      #pragma unroll
      for (int j = 0; j < 4; j++) {
        const int row = row0 + m * 16 + j;
        float v = acc[m][n][j] + bv;
        if constexpr (EPI == 1) v = fmaxf(v, 0.0f);
        if constexpr (EPI <= 1) Cb[(size_t)row * N + col] = f2bf(v);
        else                    Cf[(size_t)row * N + col] += v;
      }
    }
  }
}

// ---------------------------------------------------------------------------
// Flash attention, swapped-QK^T design.
// grid = B*H*(S/64); block 256 = 4 waves x 16 q-rows. KV tile = 64.
// K and V^T staged via global_load_lds with pre-swizzled global source.
// ---------------------------------------------------------------------------
__global__ __launch_bounds__(256, 4)
void attn(const u16* __restrict__ QKV, const u16* __restrict__ VTg,
          u16* __restrict__ Octx,
          const int* __restrict__ mask, const int* __restrict__ flags) {
  __shared__ u16 Ks[64 * 64];
  __shared__ u16 VTs[64 * 64];
  __shared__ u16 Ps[4 * 16 * 64];
  const int tid = threadIdx.x, lane = tid & 63, wv = tid >> 6;
  const int l16 = lane & 15, lhi = lane >> 4;
  const int bid = blockIdx.x;
  const int pair = bid >> 4, qblk = bid & 15;
  const int b = pair >> 4, h = pair & 15;
  const int hoff = h * DH;
  const int q0 = qblk * 64 + wv * 16;
  const size_t tokbase = (size_t)b * SEQ;
  const size_t vbase = ((size_t)b * 1024 + hoff) * SEQ;

  // Q fragments: lane's q-col = q0 + l16
  bf16x8 qf[2];
  #pragma unroll
  for (int ds = 0; ds < 2; ds++)
    qf[ds] = *(const bf16x8*)&QKV[(tokbase + q0 + l16) * QKVLD + hoff + ds * 32 + lhi * 8];

  f32x4 oacc[4];           // [nt]: O rows q=lhi*4+j, cols d=nt*16+l16
  #pragma unroll
  for (int nt = 0; nt < 4; nt++)
    #pragma unroll
    for (int j = 0; j < 4; j++) oacc[nt][j] = 0.0f;
  float mrun = -1e30f, lrun = 0.0f;   // stats for q = q0 + l16

  const int allone = flags[b];
  char* PwB = (char*)(Ps + wv * (16 * 64));
  char* KsB = (char*)Ks;
  char* VTB = (char*)VTs;
  const int xw = (l16 & 7) << 4;

  // staging indices: idx = p*256+tid; row = idx>>3; cb = idx&7; cbx = cb^(row&7)
  const int srow0 = tid >> 3, scb0 = (tid & 7) ^ (srow0 & 7);
  const int srow1 = (tid + 256) >> 3, scb1 = (tid & 7) ^ (srow1 & 7);
  const int shfl_src = (lane & 48) + ((lane >> 4) << 2);  // +j

  for (int kt = 0; kt < SEQ; kt += 64) {
    __syncthreads();
    async16((char*)Ks + tid * 16,
            &QKV[(tokbase + kt + srow0) * QKVLD + 1024 + hoff + scb0 * 8]);
    async16((char*)Ks + 4096 + tid * 16,
            &QKV[(tokbase + kt + srow1) * QKVLD + 1024 + hoff + scb1 * 8]);
    async16((char*)VTs + tid * 16, &VTg[vbase + (size_t)srow0 * SEQ + kt + scb0 * 8]);
    async16((char*)VTs + 4096 + tid * 16, &VTg[vbase + (size_t)srow1 * SEQ + kt + scb1 * 8]);
    __syncthreads();

    // S^T = K Q^T : sacc[nt] rows k=nt*16+lhi*4+j, col q=l16
    f32x4 sacc[4];
    #pragma unroll
    for (int nt = 0; nt < 4; nt++)
      #pragma unroll
      for (int j = 0; j < 4; j++) sacc[nt][j] = 0.0f;
    #pragma unroll
    for (int ds = 0; ds < 2; ds++) {
      bf16x8 kf[4];
      #pragma unroll
      for (int nt = 0; nt < 4; nt++) {
        const int rk = nt * 16 + l16;
        kf[nt] = *(const bf16x8*)(KsB + ((rk * 128 + ds * 64 + lhi * 16) ^ ((rk & 7) << 4)));
      }
      #pragma unroll
      for (int nt = 0; nt < 4; nt++)
        sacc[nt] = __builtin_amdgcn_mfma_f32_16x16x32_bf16(kf[nt], qf[ds], sacc[nt], 0, 0, 0);
    }
    #pragma unroll
    for (int nt = 0; nt < 4; nt++)
      #pragma unroll
      for (int j = 0; j < 4; j++) sacc[nt][j] *= 0.125f;

    if (!allone) {  // general-mask slow path (unused in this test)
      const int qg = q0 + l16;
      #pragma unroll
      for (int nt = 0; nt < 4; nt++)
        #pragma unroll
        for (int j = 0; j < 4; j++) {
          const int kc = kt + nt * 16 + lhi * 4 + j;
          if (mask[(tokbase + qg) * SEQ + kc] == 0) sacc[nt][j] = -1e9f;
        }
    }

    // online softmax for q = q0 + l16 (k spread over nt,j in-lane and lhi cross-lane)
    float tmax = -1e30f;
    #pragma unroll
    for (int nt = 0; nt < 4; nt++)
      #pragma unroll
      for (int j = 0; j < 4; j++) tmax = fmaxf(tmax, sacc[nt][j]);
    tmax = fmaxf(tmax, __shfl_xor(tmax, 16));
    tmax = fmaxf(tmax, __shfl_xor(tmax, 32));
    const float mnew = fmaxf(mrun, tmax);
    const float corr = __expf(mrun - mnew);
    float p[4][4];
    float tsum = 0.0f;
    #pragma unroll
    for (int nt = 0; nt < 4; nt++)
      #pragma unroll
      for (int j = 0; j < 4; j++) { p[nt][j] = __expf(sacc[nt][j] - mnew); tsum += p[nt][j]; }
    tsum += __shfl_xor(tsum, 16);
    tsum += __shfl_xor(tsum, 32);
    lrun = lrun * corr + tsum;
    mrun = mnew;

    // pack P row q=l16: k = nt*16 + lhi*4 + j  ->  b64 stores
    #pragma unroll
    for (int nt = 0; nt < 4; nt++) {
      const uint32_t lo = (uint32_t)f2bf(p[nt][0]) | ((uint32_t)f2bf(p[nt][1]) << 16);
      const uint32_t hi = (uint32_t)f2bf(p[nt][2]) | ((uint32_t)f2bf(p[nt][3]) << 16);
      *(uint64_t*)(PwB + ((l16 * 128 + nt * 32 + lhi * 8) ^ xw)) =
          (uint64_t)lo | ((uint64_t)hi << 32);
    }

    // redistribute corr to O-row layout (q = lhi*4+j) and rescale O
    float cj[4];
    #pragma unroll
    for (int j = 0; j < 4; j++) cj[j] = __shfl(corr, shfl_src + j);
    #pragma unroll
    for (int nt = 0; nt < 4; nt++)
      #pragma unroll
      for (int j = 0; j < 4; j++) oacc[nt][j] *= cj[j];

    // O += P V   (pf: A-frag rows q=l16; vf: B-frag cols d)
    #pragma unroll
    for (int ksl = 0; ksl < 2; ksl++) {
      const bf16x8 pf = *(const bf16x8*)(PwB + ((l16 * 128 + ksl * 64 + lhi * 16) ^ xw));
      #pragma unroll
      for (int nt = 0; nt < 4; nt++) {
        const int dr = nt * 16 + l16;
        const bf16x8 vf = *(const bf16x8*)(VTB + ((dr * 128 + ksl * 64 + lhi * 16) ^ ((dr & 7) << 4)));
        oacc[nt] = __builtin_amdgcn_mfma_f32_16x16x32_bf16(pf, vf, oacc[nt], 0, 0, 0);
      }
    }
  }

  const float linv = 1.0f / lrun;
  float lj[4];
  #pragma unroll
  for (int j = 0; j < 4; j++) lj[j] = __shfl(linv, shfl_src + j);
  #pragma unroll
  for (int j = 0; j < 4; j++) {
    const size_t rowg = (tokbase + q0 + lhi * 4 + j) * DM + hoff;
    #pragma unroll
    for (int nt = 0; nt < 4; nt++)
      Octx[rowg + nt * 16 + l16] = f2bf(oacc[nt][j] * lj[j]);
  }
}

// ---------------------------------------------------------------------------
// Orchestration
// ---------------------------------------------------------------------------
extern "C" void kernel_launch(void* const* d_in, const int* in_sizes, int n_in,
                              void* d_out, int out_size, void* d_ws, size_t ws_size,
                              hipStream_t stream) {
  const float* x    = (const float*)d_in[0];
  const int*   mask = (const int*)d_in[1];
  const float* wq = (const float*)d_in[2];
  const float* bq = (const float*)d_in[3];
  const float* wk = (const float*)d_in[4];
  const float* bk = (const float*)d_in[5];
  const float* wvp = (const float*)d_in[6];
  const float* bv = (const float*)d_in[7];
  const float* wo = (const float*)d_in[8];
  const float* bo = (const float*)d_in[9];
  const float* w1 = (const float*)d_in[10];
  const float* b1 = (const float*)d_in[11];
  const float* w2 = (const float*)d_in[12];
  const float* b2 = (const float*)d_in[13];
  const float* ln1g = (const float*)d_in[14];
  const float* ln1b = (const float*)d_in[15];
  const float* ln2g = (const float*)d_in[16];
  const float* ln2b = (const float*)d_in[17];
  const float* lnfg = (const float*)d_in[18];
  const float* lnfb = (const float*)d_in[19];

  char* ws = (char*)d_ws;
  float* xbuf = (float*)(ws);                        // 16 MB f32 residual
  u16* xn1  = (u16*)(ws + ((size_t)16 << 20));       // 8 MB
  u16* xn2  = (u16*)(ws + ((size_t)24 << 20));       // 8 MB
  u16* qkv  = (u16*)(ws + ((size_t)32 << 20));       // 24 MB [tok][3072]
  u16* ctx  = (u16*)(ws + ((size_t)56 << 20));       // 8 MB
  u16* hb   = (u16*)(ws + ((size_t)32 << 20));       // 32 MB alias (qkv+ctx dead by FFN)
  u16* wqkvT= (u16*)(ws + ((size_t)64 << 20));       // 6 MB [3072][1024]
  u16* woT  = (u16*)(ws + ((size_t)70 << 20));       // 2 MB
  u16* w1T  = (u16*)(ws + ((size_t)72 << 20));       // 8 MB
  u16* w2T  = (u16*)(ws + ((size_t)80 << 20));       // 8 MB
  u16* vT   = (u16*)(ws + ((size_t)88 << 20));       // 8 MB [(b*1024+hd)][s]
  float* bqkv = (float*)(ws + ((size_t)96 << 20));   // 12 KB
  int* flags  = (int*)(ws + ((size_t)96 << 20) + 65536);

  hipMemcpyAsync(xbuf, x, (size_t)NTOK * DM * sizeof(float),
                 hipMemcpyDeviceToDevice, stream);
  flags_init<<<1, 64, 0, stream>>>(flags);
  mask_flags<<<1024, 256, 0, stream>>>(mask, flags);

  auto wgs = [](int M, int N) { return dim3((unsigned)((M >> 7) * (N >> 7))); };

  for (int i = 0; i < DEPTH; i++) {
    convT<<<dim3(32, 32),  256, 0, stream>>>(wq  + (size_t)i * DM * DM,  wqkvT,                 DM,  DM);
    convT<<<dim3(32, 32),  256, 0, stream>>>(wk  + (size_t)i * DM * DM,  wqkvT + 1024 * 1024,   DM,  DM);
    convT<<<dim3(32, 32),  256, 0, stream>>>(wvp + (size_t)i * DM * DM,  wqkvT + 2048 * 1024,   DM,  DM);
    convT<<<dim3(32, 32),  256, 0, stream>>>(wo  + (size_t)i * DM * DM,  woT, DM,  DM);
    convT<<<dim3(128, 32), 256, 0, stream>>>(w1  + (size_t)i * DM * DFF, w1T, DM,  DFF);
    convT<<<dim3(32, 128), 256, 0, stream>>>(w2  + (size_t)i * DFF * DM, w2T, DFF, DM);
    bcat<<<12, 256, 0, stream>>>(bq + i * DM, bk + i * DM, bv + i * DM, bqkv);

    ln_dual<<<NTOK, 256, 0, stream>>>(xbuf, ln1g + i * DM, ln1b + i * DM,
                                      ln2g + i * DM, ln2b + i * DM, xn1, xn2);

    // fused QKV projection: [4096 x 3072 x 1024], grid 768 (3 blocks/CU)
    gemm_bt<0><<<wgs(NTOK, QKVLD), 256, 0, stream>>>(xn1, wqkvT, bqkv, qkv, nullptr,
                                                     NTOK, QKVLD, DM);
    vtrans<<<dim3(16, 16, 4), 256, 0, stream>>>(qkv, vT);

    attn<<<1024, 256, 0, stream>>>(qkv, vT, ctx, mask, flags);

    gemm_bt<2><<<wgs(NTOK, DM), 256, 0, stream>>>(ctx, woT, bo + i * DM, nullptr, xbuf,
                                                  NTOK, DM, DM);
    gemm_bt<1><<<wgs(NTOK, DFF), 256, 0, stream>>>(xn2, w1T, b1 + i * DFF, hb, nullptr,
                                                   NTOK, DFF, DM);
    gemm_bt<2><<<wgs(NTOK, DM), 256, 0, stream>>>(hb, w2T, b2 + i * DM, nullptr, xbuf,
                                                  NTOK, DM, DFF);
  }

  ln_final<<<NTOK, 256, 0, stream>>>(xbuf, lnfg, lnfb, (float*)d_out);
}

// Round 4
// 1674.288 us; speedup vs baseline: 1.4667x; 1.1474x over previous
//
#include <hip/hip_runtime.h>
#include <hip/hip_bf16.h>
#include <stdint.h>

#define DEPTH 6
#define DM 1024
#define DFF 4096
#define NH 16
#define DH 64
#define BATCH 4
#define SEQ 1024
#define NTOK (BATCH*SEQ)
#define QKVLD 3072

using bf16x8 = __attribute__((ext_vector_type(8))) short;
using f32x4  = __attribute__((ext_vector_type(4))) float;
typedef unsigned short u16;

__device__ __forceinline__ u16 f2bf(float f) {
  union { float f; uint32_t u; } v; v.f = f;
  return (u16)((v.u + 0x7FFFu + ((v.u >> 16) & 1u)) >> 16);
}

// async global->LDS, 16B per lane. LDS dest must be wave-uniform base + lane*16.
__device__ __forceinline__ void async16(void* lds, const void* g) {
  __builtin_amdgcn_global_load_lds(
      (__attribute__((address_space(1))) void*)(unsigned long long)g,
      (__attribute__((address_space(3))) void*)(unsigned int)(unsigned long long)lds,
      16, 0, 0);
}

// ---------------------------------------------------------------------------
// prep: ALL weight conversions for one layer in ONE dispatch.
//   blocks     0.. 3071 : wq|wk|wv -> wqkvT   (3 x 1024x1024)
//   blocks  3072.. 4095 : wo -> woT
//   blocks  4096.. 8191 : w1 (1024x4096) -> w1T [4096][1024]
//   blocks  8192..12287 : w2 (4096x1024) -> w2T [1024][4096]
//   blocks 12288..12299 : bias concat bq|bk|bv -> bqkv[3072]
// ---------------------------------------------------------------------------
__global__ __launch_bounds__(256)
void prep(const float* __restrict__ wq, const float* __restrict__ wk,
          const float* __restrict__ wv, const float* __restrict__ wo,
          const float* __restrict__ w1, const float* __restrict__ w2,
          const float* __restrict__ bq, const float* __restrict__ bk,
          const float* __restrict__ bv,
          u16* __restrict__ wqkvT, u16* __restrict__ woT,
          u16* __restrict__ w1T, u16* __restrict__ w2T,
          float* __restrict__ bqkv) {
  const int bid = blockIdx.x;
  if (bid >= 12288) {
    const int t = (bid - 12288) * 256 + threadIdx.x;  // 0..3071
    bqkv[t] = t < 1024 ? bq[t] : (t < 2048 ? bk[t - 1024] : bv[t - 2048]);
    return;
  }
  const float* w; u16* wt; int K, N, tile;
  if (bid < 3072)      { const int r = bid >> 10;
                         w = r == 0 ? wq : (r == 1 ? wk : wv);
                         wt = wqkvT + (size_t)r * 1024 * 1024; K = 1024; N = 1024; tile = bid & 1023; }
  else if (bid < 4096) { w = wo; wt = woT; K = 1024; N = 1024; tile = bid - 3072; }
  else if (bid < 8192) { w = w1; wt = w1T; K = 1024; N = 4096; tile = bid - 4096; }
  else                 { w = w2; wt = w2T; K = 4096; N = 1024; tile = bid - 8192; }
  const int ntn = N >> 5;
  const int k0 = (tile / ntn) << 5, n0 = (tile % ntn) << 5;

  __shared__ u16 t[32][33];
  const int tx = threadIdx.x & 31, ty = threadIdx.x >> 5;
  #pragma unroll
  for (int r = ty; r < 32; r += 8)
    t[r][tx] = f2bf(w[(size_t)(k0 + r) * N + n0 + tx]);
  __syncthreads();
  #pragma unroll
  for (int r = ty; r < 32; r += 8)
    wt[(size_t)(n0 + r) * K + k0 + tx] = t[tx][r];
}

// ---------------------------------------------------------------------------
// V-transpose: qkv[tok][3072] section 2048.. -> vt[(b*1024+hd)][s]  (bf16)
// ---------------------------------------------------------------------------
__global__ __launch_bounds__(256)
void vtrans(const u16* __restrict__ qkv, u16* __restrict__ vt) {
  __shared__ u16 t[64][72];
  const int s0 = blockIdx.x * 64, c0 = blockIdx.y * 64, b = blockIdx.z;
  const int r = threadIdx.x >> 2, cq = threadIdx.x & 3;
  const u16* src = qkv + ((size_t)(b * SEQ + s0 + r)) * QKVLD + 2048 + c0 + cq * 16;
  *(bf16x8*)&t[r][cq * 16]     = *(const bf16x8*)(src);
  *(bf16x8*)&t[r][cq * 16 + 8] = *(const bf16x8*)(src + 8);
  __syncthreads();
  bf16x8 a, bvec;
  #pragma unroll
  for (int i = 0; i < 8; i++) a[i] = (short)t[cq * 16 + i][r];
  #pragma unroll
  for (int i = 0; i < 8; i++) bvec[i] = (short)t[cq * 16 + 8 + i][r];
  u16* dst = vt + ((size_t)(b * 1024 + c0 + r)) * SEQ + s0 + cq * 16;
  *(bf16x8*)dst = a;
  *(bf16x8*)(dst + 8) = bvec;
}

// ---------------------------------------------------------------------------
// Mask all-ones flags (per batch)
// ---------------------------------------------------------------------------
__global__ void flags_init(int* flags) {
  if (threadIdx.x < BATCH) flags[threadIdx.x] = 1;
}
__global__ void mask_flags(const int* __restrict__ mask, int* __restrict__ flags) {
  const size_t n = (size_t)BATCH * SEQ * SEQ;
  for (size_t i = (size_t)blockIdx.x * 256 + threadIdx.x; i < n; i += (size_t)gridDim.x * 256)
    if (mask[i] == 0) flags[i / ((size_t)SEQ * SEQ)] = 0;
}

// ---------------------------------------------------------------------------
// Dual LayerNorm: x f32 -> o1,o2 bf16
// ---------------------------------------------------------------------------
__global__ __launch_bounds__(256)
void ln_dual(const float* __restrict__ x,
             const float* __restrict__ g1, const float* __restrict__ b1v,
             const float* __restrict__ g2, const float* __restrict__ b2v,
             u16* __restrict__ o1, u16* __restrict__ o2) {
  const int row = blockIdx.x, tid = threadIdx.x;
  const float4 v = ((const float4*)(x + (size_t)row * DM))[tid];
  float s = v.x + v.y + v.z + v.w;
  float sq = v.x*v.x + v.y*v.y + v.z*v.z + v.w*v.w;
  #pragma unroll
  for (int o = 32; o; o >>= 1) { s += __shfl_xor(s, o); sq += __shfl_xor(sq, o); }
  __shared__ float red[8];
  const int lane = tid & 63, w = tid >> 6;
  if (lane == 0) { red[w] = s; red[4 + w] = sq; }
  __syncthreads();
  s = red[0] + red[1] + red[2] + red[3];
  sq = red[4] + red[5] + red[6] + red[7];
  const float mean = s * (1.0f / DM);
  const float rinv = rsqrtf(sq * (1.0f / DM) - mean * mean + 1e-5f);
  const float4 G1 = ((const float4*)g1)[tid], B1 = ((const float4*)b1v)[tid];
  const float4 G2 = ((const float4*)g2)[tid], B2 = ((const float4*)b2v)[tid];
  const float n0 = (v.x - mean) * rinv, n1 = (v.y - mean) * rinv;
  const float n2 = (v.z - mean) * rinv, n3 = (v.w - mean) * rinv;
  ushort4 a, bb;
  a.x = f2bf(n0*G1.x + B1.x); a.y = f2bf(n1*G1.y + B1.y);
  a.z = f2bf(n2*G1.z + B1.z); a.w = f2bf(n3*G1.w + B1.w);
  bb.x = f2bf(n0*G2.x + B2.x); bb.y = f2bf(n1*G2.y + B2.y);
  bb.z = f2bf(n2*G2.z + B2.z); bb.w = f2bf(n3*G2.w + B2.w);
  ((ushort4*)(o1 + (size_t)row * DM))[tid] = a;
  ((ushort4*)(o2 + (size_t)row * DM))[tid] = bb;
}

__global__ __launch_bounds__(256)
void ln_final(const float* __restrict__ x, const float* __restrict__ g,
              const float* __restrict__ b, float* __restrict__ out) {
  const int row = blockIdx.x, tid = threadIdx.x;
  const float4 v = ((const float4*)(x + (size_t)row * DM))[tid];
  float s = v.x + v.y + v.z + v.w;
  float sq = v.x*v.x + v.y*v.y + v.z*v.z + v.w*v.w;
  #pragma unroll
  for (int o = 32; o; o >>= 1) { s += __shfl_xor(s, o); sq += __shfl_xor(sq, o); }
  __shared__ float red[8];
  const int lane = tid & 63, w = tid >> 6;
  if (lane == 0) { red[w] = s; red[4 + w] = sq; }
  __syncthreads();
  s = red[0] + red[1] + red[2] + red[3];
  sq = red[4] + red[5] + red[6] + red[7];
  const float mean = s * (1.0f / DM);
  const float rinv = rsqrtf(sq * (1.0f / DM) - mean * mean + 1e-5f);
  const float4 G = ((const float4*)g)[tid], B = ((const float4*)b)[tid];
  float4 o;
  o.x = (v.x - mean) * rinv * G.x + B.x;
  o.y = (v.y - mean) * rinv * G.y + B.y;
  o.z = (v.z - mean) * rinv * G.z + B.z;
  o.w = (v.w - mean) * rinv * G.w + B.w;
  ((float4*)(out + (size_t)row * DM))[tid] = o;
}

// ---------------------------------------------------------------------------
// GEMM: C[M,N] = A[M,K](bf16) * BT[N,K]^T(bf16) + bias.
// BM=128 fixed; BN templated (128 or 64).
//   BN=128: 4 waves as 2x2, per-wave 64x64 (acc[4][4])
//   BN= 64: 4 waves as 4x1, per-wave 32x64 (acc[2][4]) -> 2x grid for N=1024
// EPI: 0 = bias->bf16, 1 = bias+relu->bf16, 2 = bias+residual add into f32 buf
// ---------------------------------------------------------------------------
template<int EPI, int BN>
__global__ __launch_bounds__(256)
void gemm_bt(const u16* __restrict__ A, const u16* __restrict__ BT,
             const float* __restrict__ bias,
             u16* __restrict__ Cb, float* __restrict__ Cf,
             int M, int N, int K) {
  constexpr int WCn = BN / 64;     // wave-cols
  constexpr int WR  = 4 / WCn;     // wave-rows
  constexpr int MF  = 8 / WR;      // 16-row frags per wave
  constexpr int WRS = 128 / WR;    // rows per wave
  __shared__ u16 As[128 * 32];
  __shared__ u16 Bs[BN * 32];
  const int tid = threadIdx.x;
  const int lane = tid & 63, wave = tid >> 6;
  const int wr = wave / WCn, wc = wave % WCn;
  const int l16 = lane & 15, lhi = lane >> 4;

  const int ntn = N / BN;
  const int nwg = (M >> 7) * ntn;
  int wg = (int)blockIdx.x;
  if ((nwg & 7) == 0) { const int q = nwg >> 3; wg = (wg & 7) * q + (wg >> 3); }
  const int tm = wg / ntn, tn = wg % ntn;

  const int srow = tid >> 2, sc = (tid & 3) * 8;
  const u16* Ag0 = A  + (size_t)(tm * 128 + srow) * K + sc;
  const u16* Bg0 = BT + (size_t)(tn * BN + srow) * K + sc;
  const size_t rstep = (size_t)64 * K;
  u16* As0 = As + tid * 8;  u16* As1 = As + 2048 + tid * 8;
  u16* Bs0 = Bs + tid * 8;  u16* Bs1 = Bs + 2048 + tid * 8;

  f32x4 acc[MF][4];
  #pragma unroll
  for (int m = 0; m < MF; m++)
    #pragma unroll
    for (int n = 0; n < 4; n++)
      #pragma unroll
      for (int j = 0; j < 4; j++) acc[m][n][j] = 0.0f;

  for (int k0 = 0; k0 < K; k0 += 32) {
    __syncthreads();
    async16(As0, Ag0 + k0);
    async16(As1, Ag0 + rstep + k0);
    async16(Bs0, Bg0 + k0);
    if constexpr (BN == 128) async16(Bs1, Bg0 + rstep + k0);
    __syncthreads();
    bf16x8 af[MF], bfv[4];
    #pragma unroll
    for (int m = 0; m < MF; m++)
      af[m] = *(const bf16x8*)&As[(wr * WRS + m * 16 + l16) * 32 + lhi * 8];
    #pragma unroll
    for (int n = 0; n < 4; n++)
      bfv[n] = *(const bf16x8*)&Bs[(wc * 64 + n * 16 + l16) * 32 + lhi * 8];
    #pragma unroll
    for (int m = 0; m < MF; m++)
      #pragma unroll
      for (int n = 0; n < 4; n++)
        acc[m][n] = __builtin_amdgcn_mfma_f32_16x16x32_bf16(af[m], bfv[n], acc[m][n], 0, 0, 0);
  }

  const int row0 = tm * 128 + wr * WRS + lhi * 4;
  const int col0 = tn * BN + wc * 64 + l16;
  #pragma unroll
  for (int n = 0; n < 4; n++) {
    const int col = col0 + n * 16;
    const float bv = bias[col];
    #pragma unroll
    for (int m = 0; m < MF; m++) {
      #pragma unroll
      for (int j = 0; j < 4; j++) {
        const int row = row0 + m * 16 + j;
        float v = acc[m][n][j] + bv;
        if constexpr (EPI == 1) v = fmaxf(v, 0.0f);
        if constexpr (EPI <= 1) Cb[(size_t)row * N + col] = f2bf(v);
        else                    Cf[(size_t)row * N + col] += v;
      }
    }
  }
}

// ---------------------------------------------------------------------------
// Flash attention, swapped-QK^T design.
// grid = B*H*(S/64); block 256 = 4 waves x 16 q-rows. KV tile = 64.
// K and V^T staged via global_load_lds with pre-swizzled global source.
// ---------------------------------------------------------------------------
__global__ __launch_bounds__(256, 4)
void attn(const u16* __restrict__ QKV, const u16* __restrict__ VTg,
          u16* __restrict__ Octx,
          const int* __restrict__ mask, const int* __restrict__ flags) {
  __shared__ u16 Ks[64 * 64];
  __shared__ u16 VTs[64 * 64];
  __shared__ u16 Ps[4 * 16 * 64];
  const int tid = threadIdx.x, lane = tid & 63, wv = tid >> 6;
  const int l16 = lane & 15, lhi = lane >> 4;
  const int bid = blockIdx.x;
  const int pair = bid >> 4, qblk = bid & 15;
  const int b = pair >> 4, h = pair & 15;
  const int hoff = h * DH;
  const int q0 = qblk * 64 + wv * 16;
  const size_t tokbase = (size_t)b * SEQ;
  const size_t vbase = ((size_t)b * 1024 + hoff) * SEQ;

  bf16x8 qf[2];
  #pragma unroll
  for (int ds = 0; ds < 2; ds++)
    qf[ds] = *(const bf16x8*)&QKV[(tokbase + q0 + l16) * QKVLD + hoff + ds * 32 + lhi * 8];

  f32x4 oacc[4];
  #pragma unroll
  for (int nt = 0; nt < 4; nt++)
    #pragma unroll
    for (int j = 0; j < 4; j++) oacc[nt][j] = 0.0f;
  float mrun = -1e30f, lrun = 0.0f;

  const int allone = flags[b];
  char* PwB = (char*)(Ps + wv * (16 * 64));
  char* KsB = (char*)Ks;
  char* VTB = (char*)VTs;
  const int xw = (l16 & 7) << 4;

  const int srow0 = tid >> 3, scb0 = (tid & 7) ^ (srow0 & 7);
  const int srow1 = (tid + 256) >> 3, scb1 = (tid & 7) ^ (srow1 & 7);
  const int shfl_src = (lane & 48) + ((lane >> 4) << 2);

  for (int kt = 0; kt < SEQ; kt += 64) {
    __syncthreads();
    async16((char*)Ks + tid * 16,
            &QKV[(tokbase + kt + srow0) * QKVLD + 1024 + hoff + scb0 * 8]);
    async16((char*)Ks + 4096 + tid * 16,
            &QKV[(tokbase + kt + srow1) * QKVLD + 1024 + hoff + scb1 * 8]);
    async16((char*)VTs + tid * 16, &VTg[vbase + (size_t)srow0 * SEQ + kt + scb0 * 8]);
    async16((char*)VTs + 4096 + tid * 16, &VTg[vbase + (size_t)srow1 * SEQ + kt + scb1 * 8]);
    __syncthreads();

    f32x4 sacc[4];
    #pragma unroll
    for (int nt = 0; nt < 4; nt++)
      #pragma unroll
      for (int j = 0; j < 4; j++) sacc[nt][j] = 0.0f;
    #pragma unroll
    for (int ds = 0; ds < 2; ds++) {
      bf16x8 kf[4];
      #pragma unroll
      for (int nt = 0; nt < 4; nt++) {
        const int rk = nt * 16 + l16;
        kf[nt] = *(const bf16x8*)(KsB + ((rk * 128 + ds * 64 + lhi * 16) ^ ((rk & 7) << 4)));
      }
      #pragma unroll
      for (int nt = 0; nt < 4; nt++)
        sacc[nt] = __builtin_amdgcn_mfma_f32_16x16x32_bf16(kf[nt], qf[ds], sacc[nt], 0, 0, 0);
    }
    #pragma unroll
    for (int nt = 0; nt < 4; nt++)
      #pragma unroll
      for (int j = 0; j < 4; j++) sacc[nt][j] *= 0.125f;

    if (!allone) {
      const int qg = q0 + l16;
      #pragma unroll
      for (int nt = 0; nt < 4; nt++)
        #pragma unroll
        for (int j = 0; j < 4; j++) {
          const int kc = kt + nt * 16 + lhi * 4 + j;
          if (mask[(tokbase + qg) * SEQ + kc] == 0) sacc[nt][j] = -1e9f;
        }
    }

    float tmax = -1e30f;
    #pragma unroll
    for (int nt = 0; nt < 4; nt++)
      #pragma unroll
      for (int j = 0; j < 4; j++) tmax = fmaxf(tmax, sacc[nt][j]);
    tmax = fmaxf(tmax, __shfl_xor(tmax, 16));
    tmax = fmaxf(tmax, __shfl_xor(tmax, 32));
    const float mnew = fmaxf(mrun, tmax);
    const float corr = __expf(mrun - mnew);
    float p[4][4];
    float tsum = 0.0f;
    #pragma unroll
    for (int nt = 0; nt < 4; nt++)
      #pragma unroll
      for (int j = 0; j < 4; j++) { p[nt][j] = __expf(sacc[nt][j] - mnew); tsum += p[nt][j]; }
    tsum += __shfl_xor(tsum, 16);
    tsum += __shfl_xor(tsum, 32);
    lrun = lrun * corr + tsum;
    mrun = mnew;

    #pragma unroll
    for (int nt = 0; nt < 4; nt++) {
      const uint32_t lo = (uint32_t)f2bf(p[nt][0]) | ((uint32_t)f2bf(p[nt][1]) << 16);
      const uint32_t hi = (uint32_t)f2bf(p[nt][2]) | ((uint32_t)f2bf(p[nt][3]) << 16);
      *(uint64_t*)(PwB + ((l16 * 128 + nt * 32 + lhi * 8) ^ xw)) =
          (uint64_t)lo | ((uint64_t)hi << 32);
    }

    float cj[4];
    #pragma unroll
    for (int j = 0; j < 4; j++) cj[j] = __shfl(corr, shfl_src + j);
    #pragma unroll
    for (int nt = 0; nt < 4; nt++)
      #pragma unroll
      for (int j = 0; j < 4; j++) oacc[nt][j] *= cj[j];

    #pragma unroll
    for (int ksl = 0; ksl < 2; ksl++) {
      const bf16x8 pf = *(const bf16x8*)(PwB + ((l16 * 128 + ksl * 64 + lhi * 16) ^ xw));
      #pragma unroll
      for (int nt = 0; nt < 4; nt++) {
        const int dr = nt * 16 + l16;
        const bf16x8 vf = *(const bf16x8*)(VTB + ((dr * 128 + ksl * 64 + lhi * 16) ^ ((dr & 7) << 4)));
        oacc[nt] = __builtin_amdgcn_mfma_f32_16x16x32_bf16(pf, vf, oacc[nt], 0, 0, 0);
      }
    }
  }

  const float linv = 1.0f / lrun;
  float lj[4];
  #pragma unroll
  for (int j = 0; j < 4; j++) lj[j] = __shfl(linv, shfl_src + j);
  #pragma unroll
  for (int j = 0; j < 4; j++) {
    const size_t rowg = (tokbase + q0 + lhi * 4 + j) * DM + hoff;
    #pragma unroll
    for (int nt = 0; nt < 4; nt++)
      Octx[rowg + nt * 16 + l16] = f2bf(oacc[nt][j] * lj[j]);
  }
}

// ---------------------------------------------------------------------------
// Orchestration
// ---------------------------------------------------------------------------
extern "C" void kernel_launch(void* const* d_in, const int* in_sizes, int n_in,
                              void* d_out, int out_size, void* d_ws, size_t ws_size,
                              hipStream_t stream) {
  const float* x    = (const float*)d_in[0];
  const int*   mask = (const int*)d_in[1];
  const float* wq = (const float*)d_in[2];
  const float* bq = (const float*)d_in[3];
  const float* wk = (const float*)d_in[4];
  const float* bk = (const float*)d_in[5];
  const float* wvp = (const float*)d_in[6];
  const float* bv = (const float*)d_in[7];
  const float* wo = (const float*)d_in[8];
  const float* bo = (const float*)d_in[9];
  const float* w1 = (const float*)d_in[10];
  const float* b1 = (const float*)d_in[11];
  const float* w2 = (const float*)d_in[12];
  const float* b2 = (const float*)d_in[13];
  const float* ln1g = (const float*)d_in[14];
  const float* ln1b = (const float*)d_in[15];
  const float* ln2g = (const float*)d_in[16];
  const float* ln2b = (const float*)d_in[17];
  const float* lnfg = (const float*)d_in[18];
  const float* lnfb = (const float*)d_in[19];

  char* ws = (char*)d_ws;
  float* xbuf = (float*)(ws);                        // 16 MB f32 residual
  u16* xn1  = (u16*)(ws + ((size_t)16 << 20));       // 8 MB
  u16* xn2  = (u16*)(ws + ((size_t)24 << 20));       // 8 MB
  u16* qkv  = (u16*)(ws + ((size_t)32 << 20));       // 24 MB [tok][3072]
  u16* ctx  = (u16*)(ws + ((size_t)56 << 20));       // 8 MB
  u16* hb   = (u16*)(ws + ((size_t)32 << 20));       // 32 MB alias (qkv+ctx dead by FFN)
  u16* wqkvT= (u16*)(ws + ((size_t)64 << 20));       // 6 MB [3072][1024]
  u16* woT  = (u16*)(ws + ((size_t)70 << 20));       // 2 MB
  u16* w1T  = (u16*)(ws + ((size_t)72 << 20));       // 8 MB
  u16* w2T  = (u16*)(ws + ((size_t)80 << 20));       // 8 MB
  u16* vT   = (u16*)(ws + ((size_t)88 << 20));       // 8 MB [(b*1024+hd)][s]
  float* bqkv = (float*)(ws + ((size_t)96 << 20));   // 12 KB
  int* flags  = (int*)(ws + ((size_t)96 << 20) + 65536);

  hipMemcpyAsync(xbuf, x, (size_t)NTOK * DM * sizeof(float),
                 hipMemcpyDeviceToDevice, stream);
  flags_init<<<1, 64, 0, stream>>>(flags);
  mask_flags<<<1024, 256, 0, stream>>>(mask, flags);

  auto wgs128 = [](int M, int N) { return dim3((unsigned)((M >> 7) * (N >> 7))); };
  auto wgs64  = [](int M, int N) { return dim3((unsigned)((M >> 7) * (N >> 6))); };

  for (int i = 0; i < DEPTH; i++) {
    prep<<<12300, 256, 0, stream>>>(
        wq  + (size_t)i * DM * DM,  wk + (size_t)i * DM * DM,
        wvp + (size_t)i * DM * DM,  wo + (size_t)i * DM * DM,
        w1  + (size_t)i * DM * DFF, w2 + (size_t)i * DFF * DM,
        bq + i * DM, bk + i * DM, bv + i * DM,
        wqkvT, woT, w1T, w2T, bqkv);

    ln_dual<<<NTOK, 256, 0, stream>>>(xbuf, ln1g + i * DM, ln1b + i * DM,
                                      ln2g + i * DM, ln2b + i * DM, xn1, xn2);

    // fused QKV projection: [4096 x 3072 x 1024], grid 768 (3 blocks/CU)
    gemm_bt<0, 128><<<wgs128(NTOK, QKVLD), 256, 0, stream>>>(xn1, wqkvT, bqkv, qkv, nullptr,
                                                             NTOK, QKVLD, DM);
    vtrans<<<dim3(16, 16, 4), 256, 0, stream>>>(qkv, vT);

    attn<<<1024, 256, 0, stream>>>(qkv, vT, ctx, mask, flags);

    // N=1024 GEMMs use BN=64 -> grid 512 (2 blocks/CU; was 256 = 1/CU)
    gemm_bt<2, 64><<<wgs64(NTOK, DM), 256, 0, stream>>>(ctx, woT, bo + i * DM, nullptr, xbuf,
                                                        NTOK, DM, DM);
    gemm_bt<1, 128><<<wgs128(NTOK, DFF), 256, 0, stream>>>(xn2, w1T, b1 + i * DFF, hb, nullptr,
                                                           NTOK, DFF, DM);
    gemm_bt<2, 64><<<wgs64(NTOK, DM), 256, 0, stream>>>(hb, w2T, b2 + i * DM, nullptr, xbuf,
                                                        NTOK, DM, DFF);
  }

  ln_final<<<NTOK, 256, 0, stream>>>(xbuf, lnfg, lnfb, (float*)d_out);
}

// Round 5
// 1523.321 us; speedup vs baseline: 1.6120x; 1.0991x over previous
//
#include <hip/hip_runtime.h>
#include <hip/hip_bf16.h>
#include <stdint.h>

#define DEPTH 6
#define DM 1024
#define DFF 4096
#define NH 16
#define DH 64
#define BATCH 4
#define SEQ 1024
#define NTOK (BATCH*SEQ)
#define QKVLD 3072

using bf16x8 = __attribute__((ext_vector_type(8))) short;
using f32x4  = __attribute__((ext_vector_type(4))) float;
typedef unsigned short u16;

__device__ __forceinline__ u16 f2bf(float f) {
  union { float f; uint32_t u; } v; v.f = f;
  return (u16)((v.u + 0x7FFFu + ((v.u >> 16) & 1u)) >> 16);
}

// async global->LDS, 16B per lane. LDS dest must be wave-uniform base + lane*16.
__device__ __forceinline__ void async16(void* lds, const void* g) {
  __builtin_amdgcn_global_load_lds(
      (__attribute__((address_space(1))) void*)(unsigned long long)g,
      (__attribute__((address_space(3))) void*)(unsigned int)(unsigned long long)lds,
      16, 0, 0);
}

// ---------------------------------------------------------------------------
// prep: ALL weight conversions for one layer in ONE dispatch.
// ---------------------------------------------------------------------------
__global__ __launch_bounds__(256)
void prep(const float* __restrict__ wq, const float* __restrict__ wk,
          const float* __restrict__ wv, const float* __restrict__ wo,
          const float* __restrict__ w1, const float* __restrict__ w2,
          const float* __restrict__ bq, const float* __restrict__ bk,
          const float* __restrict__ bv,
          u16* __restrict__ wqkvT, u16* __restrict__ woT,
          u16* __restrict__ w1T, u16* __restrict__ w2T,
          float* __restrict__ bqkv) {
  const int bid = blockIdx.x;
  if (bid >= 12288) {
    const int t = (bid - 12288) * 256 + threadIdx.x;  // 0..3071
    bqkv[t] = t < 1024 ? bq[t] : (t < 2048 ? bk[t - 1024] : bv[t - 2048]);
    return;
  }
  const float* w; u16* wt; int K, N, tile;
  if (bid < 3072)      { const int r = bid >> 10;
                         w = r == 0 ? wq : (r == 1 ? wk : wv);
                         wt = wqkvT + (size_t)r * 1024 * 1024; K = 1024; N = 1024; tile = bid & 1023; }
  else if (bid < 4096) { w = wo; wt = woT; K = 1024; N = 1024; tile = bid - 3072; }
  else if (bid < 8192) { w = w1; wt = w1T; K = 1024; N = 4096; tile = bid - 4096; }
  else                 { w = w2; wt = w2T; K = 4096; N = 1024; tile = bid - 8192; }
  const int ntn = N >> 5;
  const int k0 = (tile / ntn) << 5, n0 = (tile % ntn) << 5;

  __shared__ u16 t[32][33];
  const int tx = threadIdx.x & 31, ty = threadIdx.x >> 5;
  #pragma unroll
  for (int r = ty; r < 32; r += 8)
    t[r][tx] = f2bf(w[(size_t)(k0 + r) * N + n0 + tx]);
  __syncthreads();
  #pragma unroll
  for (int r = ty; r < 32; r += 8)
    wt[(size_t)(n0 + r) * K + k0 + tx] = t[tx][r];
}

// ---------------------------------------------------------------------------
// V-transpose: qkv[tok][3072] section 2048.. -> vt[(b*1024+hd)][s]  (bf16)
// ---------------------------------------------------------------------------
__global__ __launch_bounds__(256)
void vtrans(const u16* __restrict__ qkv, u16* __restrict__ vt) {
  __shared__ u16 t[64][72];
  const int s0 = blockIdx.x * 64, c0 = blockIdx.y * 64, b = blockIdx.z;
  const int r = threadIdx.x >> 2, cq = threadIdx.x & 3;
  const u16* src = qkv + ((size_t)(b * SEQ + s0 + r)) * QKVLD + 2048 + c0 + cq * 16;
  *(bf16x8*)&t[r][cq * 16]     = *(const bf16x8*)(src);
  *(bf16x8*)&t[r][cq * 16 + 8] = *(const bf16x8*)(src + 8);
  __syncthreads();
  bf16x8 a, bvec;
  #pragma unroll
  for (int i = 0; i < 8; i++) a[i] = (short)t[cq * 16 + i][r];
  #pragma unroll
  for (int i = 0; i < 8; i++) bvec[i] = (short)t[cq * 16 + 8 + i][r];
  u16* dst = vt + ((size_t)(b * 1024 + c0 + r)) * SEQ + s0 + cq * 16;
  *(bf16x8*)dst = a;
  *(bf16x8*)(dst + 8) = bvec;
}

// ---------------------------------------------------------------------------
// Mask all-ones flags (per batch)
// ---------------------------------------------------------------------------
__global__ void flags_init(int* flags) {
  if (threadIdx.x < BATCH) flags[threadIdx.x] = 1;
}
__global__ void mask_flags(const int* __restrict__ mask, int* __restrict__ flags) {
  const size_t n = (size_t)BATCH * SEQ * SEQ;
  for (size_t i = (size_t)blockIdx.x * 256 + threadIdx.x; i < n; i += (size_t)gridDim.x * 256)
    if (mask[i] == 0) flags[i / ((size_t)SEQ * SEQ)] = 0;
}

// ---------------------------------------------------------------------------
// Dual LayerNorm: x f32 -> o1,o2 bf16
// ---------------------------------------------------------------------------
__global__ __launch_bounds__(256)
void ln_dual(const float* __restrict__ x,
             const float* __restrict__ g1, const float* __restrict__ b1v,
             const float* __restrict__ g2, const float* __restrict__ b2v,
             u16* __restrict__ o1, u16* __restrict__ o2) {
  const int row = blockIdx.x, tid = threadIdx.x;
  const float4 v = ((const float4*)(x + (size_t)row * DM))[tid];
  float s = v.x + v.y + v.z + v.w;
  float sq = v.x*v.x + v.y*v.y + v.z*v.z + v.w*v.w;
  #pragma unroll
  for (int o = 32; o; o >>= 1) { s += __shfl_xor(s, o); sq += __shfl_xor(sq, o); }
  __shared__ float red[8];
  const int lane = tid & 63, w = tid >> 6;
  if (lane == 0) { red[w] = s; red[4 + w] = sq; }
  __syncthreads();
  s = red[0] + red[1] + red[2] + red[3];
  sq = red[4] + red[5] + red[6] + red[7];
  const float mean = s * (1.0f / DM);
  const float rinv = rsqrtf(sq * (1.0f / DM) - mean * mean + 1e-5f);
  const float4 G1 = ((const float4*)g1)[tid], B1 = ((const float4*)b1v)[tid];
  const float4 G2 = ((const float4*)g2)[tid], B2 = ((const float4*)b2v)[tid];
  const float n0 = (v.x - mean) * rinv, n1 = (v.y - mean) * rinv;
  const float n2 = (v.z - mean) * rinv, n3 = (v.w - mean) * rinv;
  ushort4 a, bb;
  a.x = f2bf(n0*G1.x + B1.x); a.y = f2bf(n1*G1.y + B1.y);
  a.z = f2bf(n2*G1.z + B1.z); a.w = f2bf(n3*G1.w + B1.w);
  bb.x = f2bf(n0*G2.x + B2.x); bb.y = f2bf(n1*G2.y + B2.y);
  bb.z = f2bf(n2*G2.z + B2.z); bb.w = f2bf(n3*G2.w + B2.w);
  ((ushort4*)(o1 + (size_t)row * DM))[tid] = a;
  ((ushort4*)(o2 + (size_t)row * DM))[tid] = bb;
}

__global__ __launch_bounds__(256)
void ln_final(const float* __restrict__ x, const float* __restrict__ g,
              const float* __restrict__ b, float* __restrict__ out) {
  const int row = blockIdx.x, tid = threadIdx.x;
  const float4 v = ((const float4*)(x + (size_t)row * DM))[tid];
  float s = v.x + v.y + v.z + v.w;
  float sq = v.x*v.x + v.y*v.y + v.z*v.z + v.w*v.w;
  #pragma unroll
  for (int o = 32; o; o >>= 1) { s += __shfl_xor(s, o); sq += __shfl_xor(sq, o); }
  __shared__ float red[8];
  const int lane = tid & 63, w = tid >> 6;
  if (lane == 0) { red[w] = s; red[4 + w] = sq; }
  __syncthreads();
  s = red[0] + red[1] + red[2] + red[3];
  sq = red[4] + red[5] + red[6] + red[7];
  const float mean = s * (1.0f / DM);
  const float rinv = rsqrtf(sq * (1.0f / DM) - mean * mean + 1e-5f);
  const float4 G = ((const float4*)g)[tid], B = ((const float4*)b)[tid];
  float4 o;
  o.x = (v.x - mean) * rinv * G.x + B.x;
  o.y = (v.y - mean) * rinv * G.y + B.y;
  o.z = (v.z - mean) * rinv * G.z + B.z;
  o.w = (v.w - mean) * rinv * G.w + B.w;
  ((float4*)(out + (size_t)row * DM))[tid] = o;
}

// ---------------------------------------------------------------------------
// GEMM: C[M,N] = A[M,K](bf16) * BT[N,K]^T(bf16) + bias.
// 2-phase double-buffered LDS (T3 minimum recipe): STAGE(t+1) issued BEFORE
// ds_read+MFMA of tile t; single __syncthreads per tile (= vmcnt(0)+lgkm+bar).
// BM=128 fixed; BN templated (128 or 64).
// EPI: 0 = bias->bf16, 1 = bias+relu->bf16, 2 = bias+residual add into f32 buf
// ---------------------------------------------------------------------------
template<int EPI, int BN>
__global__ __launch_bounds__(256)
void gemm_bt(const u16* __restrict__ A, const u16* __restrict__ BT,
             const float* __restrict__ bias,
             u16* __restrict__ Cb, float* __restrict__ Cf,
             int M, int N, int K) {
  constexpr int WCn = BN / 64;     // wave-cols
  constexpr int WR  = 4 / WCn;     // wave-rows
  constexpr int MF  = 8 / WR;      // 16-row frags per wave
  constexpr int WRS = 128 / WR;    // rows per wave
  constexpr int ASZ = 128 * 32;    // u16 per A buffer
  constexpr int BSZ = BN * 32;     // u16 per B buffer
  __shared__ u16 As[2 * ASZ];
  __shared__ u16 Bs[2 * BSZ];
  const int tid = threadIdx.x;
  const int lane = tid & 63, wave = tid >> 6;
  const int wr = wave / WCn, wc = wave % WCn;
  const int l16 = lane & 15, lhi = lane >> 4;

  const int ntn = N / BN;
  const int nwg = (M >> 7) * ntn;
  int wg = (int)blockIdx.x;
  if ((nwg & 7) == 0) { const int q = nwg >> 3; wg = (wg & 7) * q + (wg >> 3); }
  const int tm = wg / ntn, tn = wg % ntn;

  const int srow = tid >> 2, sc = (tid & 3) * 8;
  const u16* Ag0 = A  + (size_t)(tm * 128 + srow) * K + sc;
  const u16* Bg0 = BT + (size_t)(tn * BN + srow) * K + sc;
  const size_t rstep = (size_t)64 * K;

  auto stage = [&](int buf, int k0) {
    async16(As + buf * ASZ + tid * 8, Ag0 + k0);
    async16(As + buf * ASZ + 2048 + tid * 8, Ag0 + rstep + k0);
    async16(Bs + buf * BSZ + tid * 8, Bg0 + k0);
    if constexpr (BN == 128) async16(Bs + buf * BSZ + 2048 + tid * 8, Bg0 + rstep + k0);
  };

  f32x4 acc[MF][4];
  #pragma unroll
  for (int m = 0; m < MF; m++)
    #pragma unroll
    for (int n = 0; n < 4; n++)
      #pragma unroll
      for (int j = 0; j < 4; j++) acc[m][n][j] = 0.0f;

  stage(0, 0);
  __syncthreads();          // vmcnt(0) drain + barrier: buf0 ready
  int cur = 0;
  for (int k0 = 0; k0 < K; k0 += 32) {
    if (k0 + 32 < K) stage(cur ^ 1, k0 + 32);   // prefetch next tile
    const u16* Ab = As + cur * ASZ;
    const u16* Bb = Bs + cur * BSZ;
    bf16x8 af[MF], bfv[4];
    #pragma unroll
    for (int m = 0; m < MF; m++)
      af[m] = *(const bf16x8*)&Ab[(wr * WRS + m * 16 + l16) * 32 + lhi * 8];
    #pragma unroll
    for (int n = 0; n < 4; n++)
      bfv[n] = *(const bf16x8*)&Bb[(wc * 64 + n * 16 + l16) * 32 + lhi * 8];
    #pragma unroll
    for (int m = 0; m < MF; m++)
      #pragma unroll
      for (int n = 0; n < 4; n++)
        acc[m][n] = __builtin_amdgcn_mfma_f32_16x16x32_bf16(af[m], bfv[n], acc[m][n], 0, 0, 0);
    __syncthreads();        // all reads of buf[cur] done; prefetch landed
    cur ^= 1;
  }

  const int row0 = tm * 128 + wr * WRS + lhi * 4;
  const int col0 = tn * BN + wc * 64 + l16;
  #pragma unroll
  for (int n = 0; n < 4; n++) {
    const int col = col0 + n * 16;
    const float bv = bias[col];
    #pragma unroll
    for (int m = 0; m < MF; m++) {
      #pragma unroll
      for (int j = 0; j < 4; j++) {
        const int row = row0 + m * 16 + j;
        float v = acc[m][n][j] + bv;
        if constexpr (EPI == 1) v = fmaxf(v, 0.0f);
        if constexpr (EPI <= 1) Cb[(size_t)row * N + col] = f2bf(v);
        else                    Cf[(size_t)row * N + col] += v;
      }
    }
  }
}

// ---------------------------------------------------------------------------
// Flash attention, swapped-QK^T design, 2-phase double-buffered K/V staging.
// grid = B*H*(S/64); block 256 = 4 waves x 16 q-rows. KV tile = 64.
// ---------------------------------------------------------------------------
__global__ __launch_bounds__(256, 4)
void attn(const u16* __restrict__ QKV, const u16* __restrict__ VTg,
          u16* __restrict__ Octx,
          const int* __restrict__ mask, const int* __restrict__ flags) {
  __shared__ u16 Ks[2 * 64 * 64];
  __shared__ u16 VTs[2 * 64 * 64];
  __shared__ u16 Ps[4 * 16 * 64];
  const int tid = threadIdx.x, lane = tid & 63, wv = tid >> 6;
  const int l16 = lane & 15, lhi = lane >> 4;
  const int bid = blockIdx.x;
  const int pair = bid >> 4, qblk = bid & 15;
  const int b = pair >> 4, h = pair & 15;
  const int hoff = h * DH;
  const int q0 = qblk * 64 + wv * 16;
  const size_t tokbase = (size_t)b * SEQ;
  const size_t vbase = ((size_t)b * 1024 + hoff) * SEQ;

  bf16x8 qf[2];
  #pragma unroll
  for (int ds = 0; ds < 2; ds++)
    qf[ds] = *(const bf16x8*)&QKV[(tokbase + q0 + l16) * QKVLD + hoff + ds * 32 + lhi * 8];

  f32x4 oacc[4];
  #pragma unroll
  for (int nt = 0; nt < 4; nt++)
    #pragma unroll
    for (int j = 0; j < 4; j++) oacc[nt][j] = 0.0f;
  float mrun = -1e30f, lrun = 0.0f;

  const int allone = flags[b];
  char* PwB = (char*)(Ps + wv * (16 * 64));
  const int xw = (l16 & 7) << 4;

  const int srow0 = tid >> 3, scb0 = (tid & 7) ^ (srow0 & 7);
  const int srow1 = (tid + 256) >> 3, scb1 = (tid & 7) ^ (srow1 & 7);
  const int shfl_src = (lane & 48) + ((lane >> 4) << 2);

  auto stage = [&](int buf, int kt) {
    async16((char*)Ks + buf * 8192 + tid * 16,
            &QKV[(tokbase + kt + srow0) * QKVLD + 1024 + hoff + scb0 * 8]);
    async16((char*)Ks + buf * 8192 + 4096 + tid * 16,
            &QKV[(tokbase + kt + srow1) * QKVLD + 1024 + hoff + scb1 * 8]);
    async16((char*)VTs + buf * 8192 + tid * 16,
            &VTg[vbase + (size_t)srow0 * SEQ + kt + scb0 * 8]);
    async16((char*)VTs + buf * 8192 + 4096 + tid * 16,
            &VTg[vbase + (size_t)srow1 * SEQ + kt + scb1 * 8]);
  };

  stage(0, 0);
  __syncthreads();
  int cur = 0;
  for (int kt = 0; kt < SEQ; kt += 64) {
    if (kt + 64 < SEQ) stage(cur ^ 1, kt + 64);   // prefetch next K/V tile
    char* KsB = (char*)Ks + cur * 8192;
    char* VTB = (char*)VTs + cur * 8192;

    f32x4 sacc[4];
    #pragma unroll
    for (int nt = 0; nt < 4; nt++)
      #pragma unroll
      for (int j = 0; j < 4; j++) sacc[nt][j] = 0.0f;
    #pragma unroll
    for (int ds = 0; ds < 2; ds++) {
      bf16x8 kf[4];
      #pragma unroll
      for (int nt = 0; nt < 4; nt++) {
        const int rk = nt * 16 + l16;
        kf[nt] = *(const bf16x8*)(KsB + ((rk * 128 + ds * 64 + lhi * 16) ^ ((rk & 7) << 4)));
      }
      #pragma unroll
      for (int nt = 0; nt < 4; nt++)
        sacc[nt] = __builtin_amdgcn_mfma_f32_16x16x32_bf16(kf[nt], qf[ds], sacc[nt], 0, 0, 0);
    }
    #pragma unroll
    for (int nt = 0; nt < 4; nt++)
      #pragma unroll
      for (int j = 0; j < 4; j++) sacc[nt][j] *= 0.125f;

    if (!allone) {
      const int qg = q0 + l16;
      #pragma unroll
      for (int nt = 0; nt < 4; nt++)
        #pragma unroll
        for (int j = 0; j < 4; j++) {
          const int kc = kt + nt * 16 + lhi * 4 + j;
          if (mask[(tokbase + qg) * SEQ + kc] == 0) sacc[nt][j] = -1e9f;
        }
    }

    float tmax = -1e30f;
    #pragma unroll
    for (int nt = 0; nt < 4; nt++)
      #pragma unroll
      for (int j = 0; j < 4; j++) tmax = fmaxf(tmax, sacc[nt][j]);
    tmax = fmaxf(tmax, __shfl_xor(tmax, 16));
    tmax = fmaxf(tmax, __shfl_xor(tmax, 32));
    const float mnew = fmaxf(mrun, tmax);
    const float corr = __expf(mrun - mnew);
    float p[4][4];
    float tsum = 0.0f;
    #pragma unroll
    for (int nt = 0; nt < 4; nt++)
      #pragma unroll
      for (int j = 0; j < 4; j++) { p[nt][j] = __expf(sacc[nt][j] - mnew); tsum += p[nt][j]; }
    tsum += __shfl_xor(tsum, 16);
    tsum += __shfl_xor(tsum, 32);
    lrun = lrun * corr + tsum;
    mrun = mnew;

    #pragma unroll
    for (int nt = 0; nt < 4; nt++) {
      const uint32_t lo = (uint32_t)f2bf(p[nt][0]) | ((uint32_t)f2bf(p[nt][1]) << 16);
      const uint32_t hi = (uint32_t)f2bf(p[nt][2]) | ((uint32_t)f2bf(p[nt][3]) << 16);
      *(uint64_t*)(PwB + ((l16 * 128 + nt * 32 + lhi * 8) ^ xw)) =
          (uint64_t)lo | ((uint64_t)hi << 32);
    }

    float cj[4];
    #pragma unroll
    for (int j = 0; j < 4; j++) cj[j] = __shfl(corr, shfl_src + j);
    #pragma unroll
    for (int nt = 0; nt < 4; nt++)
      #pragma unroll
      for (int j = 0; j < 4; j++) oacc[nt][j] *= cj[j];

    #pragma unroll
    for (int ksl = 0; ksl < 2; ksl++) {
      const bf16x8 pf = *(const bf16x8*)(PwB + ((l16 * 128 + ksl * 64 + lhi * 16) ^ xw));
      #pragma unroll
      for (int nt = 0; nt < 4; nt++) {
        const int dr = nt * 16 + l16;
        const bf16x8 vf = *(const bf16x8*)(VTB + ((dr * 128 + ksl * 64 + lhi * 16) ^ ((dr & 7) << 4)));
        oacc[nt] = __builtin_amdgcn_mfma_f32_16x16x32_bf16(pf, vf, oacc[nt], 0, 0, 0);
      }
    }
    __syncthreads();   // reads of buf[cur] done; prefetch landed
    cur ^= 1;
  }

  const float linv = 1.0f / lrun;
  float lj[4];
  #pragma unroll
  for (int j = 0; j < 4; j++) lj[j] = __shfl(linv, shfl_src + j);
  #pragma unroll
  for (int j = 0; j < 4; j++) {
    const size_t rowg = (tokbase + q0 + lhi * 4 + j) * DM + hoff;
    #pragma unroll
    for (int nt = 0; nt < 4; nt++)
      Octx[rowg + nt * 16 + l16] = f2bf(oacc[nt][j] * lj[j]);
  }
}

// ---------------------------------------------------------------------------
// Orchestration
// ---------------------------------------------------------------------------
extern "C" void kernel_launch(void* const* d_in, const int* in_sizes, int n_in,
                              void* d_out, int out_size, void* d_ws, size_t ws_size,
                              hipStream_t stream) {
  const float* x    = (const float*)d_in[0];
  const int*   mask = (const int*)d_in[1];
  const float* wq = (const float*)d_in[2];
  const float* bq = (const float*)d_in[3];
  const float* wk = (const float*)d_in[4];
  const float* bk = (const float*)d_in[5];
  const float* wvp = (const float*)d_in[6];
  const float* bv = (const float*)d_in[7];
  const float* wo = (const float*)d_in[8];
  const float* bo = (const float*)d_in[9];
  const float* w1 = (const float*)d_in[10];
  const float* b1 = (const float*)d_in[11];
  const float* w2 = (const float*)d_in[12];
  const float* b2 = (const float*)d_in[13];
  const float* ln1g = (const float*)d_in[14];
  const float* ln1b = (const float*)d_in[15];
  const float* ln2g = (const float*)d_in[16];
  const float* ln2b = (const float*)d_in[17];
  const float* lnfg = (const float*)d_in[18];
  const float* lnfb = (const float*)d_in[19];

  char* ws = (char*)d_ws;
  float* xbuf = (float*)(ws);                        // 16 MB f32 residual
  u16* xn1  = (u16*)(ws + ((size_t)16 << 20));       // 8 MB
  u16* xn2  = (u16*)(ws + ((size_t)24 << 20));       // 8 MB
  u16* qkv  = (u16*)(ws + ((size_t)32 << 20));       // 24 MB [tok][3072]
  u16* ctx  = (u16*)(ws + ((size_t)56 << 20));       // 8 MB
  u16* hb   = (u16*)(ws + ((size_t)32 << 20));       // 32 MB alias (qkv+ctx dead by FFN)
  u16* wqkvT= (u16*)(ws + ((size_t)64 << 20));       // 6 MB [3072][1024]
  u16* woT  = (u16*)(ws + ((size_t)70 << 20));       // 2 MB
  u16* w1T  = (u16*)(ws + ((size_t)72 << 20));       // 8 MB
  u16* w2T  = (u16*)(ws + ((size_t)80 << 20));       // 8 MB
  u16* vT   = (u16*)(ws + ((size_t)88 << 20));       // 8 MB [(b*1024+hd)][s]
  float* bqkv = (float*)(ws + ((size_t)96 << 20));   // 12 KB
  int* flags  = (int*)(ws + ((size_t)96 << 20) + 65536);

  hipMemcpyAsync(xbuf, x, (size_t)NTOK * DM * sizeof(float),
                 hipMemcpyDeviceToDevice, stream);
  flags_init<<<1, 64, 0, stream>>>(flags);
  mask_flags<<<1024, 256, 0, stream>>>(mask, flags);

  auto wgs128 = [](int M, int N) { return dim3((unsigned)((M >> 7) * (N >> 7))); };
  auto wgs64  = [](int M, int N) { return dim3((unsigned)((M >> 7) * (N >> 6))); };

  for (int i = 0; i < DEPTH; i++) {
    prep<<<12300, 256, 0, stream>>>(
        wq  + (size_t)i * DM * DM,  wk + (size_t)i * DM * DM,
        wvp + (size_t)i * DM * DM,  wo + (size_t)i * DM * DM,
        w1  + (size_t)i * DM * DFF, w2 + (size_t)i * DFF * DM,
        bq + i * DM, bk + i * DM, bv + i * DM,
        wqkvT, woT, w1T, w2T, bqkv);

    ln_dual<<<NTOK, 256, 0, stream>>>(xbuf, ln1g + i * DM, ln1b + i * DM,
                                      ln2g + i * DM, ln2b + i * DM, xn1, xn2);

    gemm_bt<0, 128><<<wgs128(NTOK, QKVLD), 256, 0, stream>>>(xn1, wqkvT, bqkv, qkv, nullptr,
                                                             NTOK, QKVLD, DM);
    vtrans<<<dim3(16, 16, 4), 256, 0, stream>>>(qkv, vT);

    attn<<<1024, 256, 0, stream>>>(qkv, vT, ctx, mask, flags);

    gemm_bt<2, 64><<<wgs64(NTOK, DM), 256, 0, stream>>>(ctx, woT, bo + i * DM, nullptr, xbuf,
                                                        NTOK, DM, DM);
    gemm_bt<1, 128><<<wgs128(NTOK, DFF), 256, 0, stream>>>(xn2, w1T, b1 + i * DFF, hb, nullptr,
                                                           NTOK, DFF, DM);
    gemm_bt<2, 64><<<wgs64(NTOK, DM), 256, 0, stream>>>(hb, w2T, b2 + i * DM, nullptr, xbuf,
                                                        NTOK, DM, DFF);
  }

  ln_final<<<NTOK, 256, 0, stream>>>(xbuf, lnfg, lnfb, (float*)d_out);
}